// Round 1
// baseline (141.696 us; speedup 1.0000x reference)
//
#include <hip/hip_runtime.h>

// TSA_24936580121000 — fused temporal self-attention, MI355X gfx950.
// Round 1: single fused MFMA kernel + weight-prepack kernel.
//
// Shapes: x[b=4][c=128][t=16][h=64][w=64], q_w/k_w[16][128], v_w[128][128].
// Per position p=(b,h,w): qkv = proj(x_p), sT = k q^T, softmax cols, outT = vT pT,
// y = gamma*out + x  (x residual re-read fp32 from global => exact when gamma==0).

#define C_  128
#define T_  16
#define H_  64
#define W_  64
#define CO_ 160          // 16 q + 16 k + 128 v
#define WT_ 16           // w positions per block
#define NPOS WT_
#define NBLK 1024        // 4 b * 64 h * 4 wtiles

typedef float  f32x4  __attribute__((ext_vector_type(4)));
typedef short  bf16x4 __attribute__((ext_vector_type(4)));
typedef short  bf16x8 __attribute__((ext_vector_type(8)));

__device__ __forceinline__ unsigned short f2bf(float f) {
    union { float f; unsigned u; } v; v.f = f;
    unsigned r = v.u + 0x7fffu + ((v.u >> 16) & 1u);   // RNE
    return (unsigned short)(r >> 16);
}
__device__ __forceinline__ float bf2f(unsigned short s) {
    union { unsigned u; float f; } v; v.u = ((unsigned)s) << 16;
    return v.f;
}

// ---------------- prepack: fp32 weights -> bf16 W2[160][128], biases b2[160] ----
__global__ __launch_bounds__(256) void tsa_prepack(
        const float* __restrict__ qw, const float* __restrict__ qb,
        const float* __restrict__ kw, const float* __restrict__ kb,
        const float* __restrict__ vw, const float* __restrict__ vb,
        unsigned short* __restrict__ W2, float* __restrict__ b2) {
    int i = blockIdx.x * 256 + threadIdx.x;      // grid 80*256 == 20480 == 160*128
    int o = i >> 7, c = i & 127;
    float v = (o < 16) ? qw[o * C_ + c] : (o < 32) ? kw[(o - 16) * C_ + c]
                                                   : vw[(o - 32) * C_ + c];
    W2[i] = f2bf(v);
    if (i < CO_) b2[i] = (i < 16) ? qb[i] : (i < 32) ? kb[i - 16] : vb[i - 32];
}

// ---------------- LDS index helpers (shorts) -----------------------------------
// staging layout: x bf16 [pos=16][t=16][c=128]
#define IDX_X(pos, t, c)  ((((pos) * T_ + (t)) * C_) + (c))
// out layout (reuses xo region): [t][w][c] padded: w-stride 132, t-stride 16*132+8
#define OS_W 132
#define OS_T (WT_ * OS_W + 8)          // 2120 shorts; 1060 dwords = 4 mod 32
#define IDX_O(t, w, c)    ((t) * OS_T + (w) * OS_W + (c))
// qk: [pos][2][t][o=16]
#define IDX_QK(pos, qk, t, o) (((((pos) * 2 + (qk)) * T_ + (t)) * 16) + (o))
// vT: [pos][c=128][t=16]
#define IDX_V(pos, c, t)  ((((pos) * C_ + (c)) * T_) + (t))

// ---------------- main fused kernel --------------------------------------------
__global__ __launch_bounds__(512) void tsa_main(
        const float* __restrict__ x, const unsigned short* __restrict__ W2,
        const float* __restrict__ b2, const float* __restrict__ gamma,
        float* __restrict__ y) {

    __shared__ __align__(16) unsigned short xo_lds[T_ * OS_T];   // 33920 sh = 66.3 KiB (>= 32768 staging)
    __shared__ __align__(16) unsigned short qk_lds[NPOS * 2 * T_ * 16];  // 16 KiB
    __shared__ __align__(16) unsigned short vT_lds[NPOS * C_ * T_];      // 64 KiB

    // XCD-chunked swizzle (nwg=1024 divisible by 8): all 4 wtiles of a (b,h)
    // row land on one XCD for 64B-line read/write sharing.
    int bid  = blockIdx.x;
    int work = (bid & 7) * (NBLK / 8) + (bid >> 3);
    int bh = work >> 2;                  // 0..255 = b*64 + h
    int wt = work & 3;                   // 4 w-tiles of 16
    int b  = bh >> 6, h = bh & 63;
    int w0 = wt * WT_;

    const size_t base = (size_t)b * C_ * T_ * H_ * W_ + (size_t)h * W_ + w0;
    const float* xb = x + base;
    float*       yb = y + base;
    // addr(c,t,w) = base + c*65536 + t*4096 + w

    const int tid = threadIdx.x;

    // ---- phase 1: stage x tile -> bf16 LDS [pos][t][c] --------------------
    {
        int cs = tid & 127;              // c   (lanes span 64 consecutive c)
        int th = tid >> 7;               // 0..3
        #pragma unroll
        for (int k = 0; k < 4; ++k) {
            int t = th * 4 + k;
            const float* p = xb + cs * (T_ * H_ * W_) + t * (H_ * W_);
            f32x4 v0 = *(const f32x4*)(p);
            f32x4 v1 = *(const f32x4*)(p + 4);
            f32x4 v2 = *(const f32x4*)(p + 8);
            f32x4 v3 = *(const f32x4*)(p + 12);
            #pragma unroll
            for (int e = 0; e < 4; ++e) {
                xo_lds[IDX_X(e,      t, cs)] = f2bf(v0[e]);
                xo_lds[IDX_X(e + 4,  t, cs)] = f2bf(v1[e]);
                xo_lds[IDX_X(e + 8,  t, cs)] = f2bf(v2[e]);
                xo_lds[IDX_X(e + 12, t, cs)] = f2bf(v3[e]);
            }
        }
    }
    __syncthreads();   // B1

    const int wv  = tid >> 6;    // wave 0..7 -> positions wv*2, wv*2+1
    const int lr  = tid & 15;    // row/col within 16x16 tile
    const int grp = (tid & 63) >> 4;   // lane group 0..3

    // ---- phase 2: projection qkv = x^T * W^T  (mfma 16x16x32 bf16) --------
    // A[t][c] frags from LDS (x region is dead after this preload).
    bf16x8 afrag[2][4];
    #pragma unroll
    for (int p = 0; p < 2; ++p) {
        int pos = wv * 2 + p;
        #pragma unroll
        for (int ks = 0; ks < 4; ++ks)
            afrag[p][ks] = *(const bf16x8*)&xo_lds[IDX_X(pos, lr, ks * 32 + grp * 8)];
    }
    float biasv[10];
    #pragma unroll
    for (int nt = 0; nt < 10; ++nt) biasv[nt] = b2[nt * 16 + lr];

    #pragma unroll
    for (int nt = 0; nt < 10; ++nt) {
        f32x4 acc[2];
        acc[0] = (f32x4){0.f, 0.f, 0.f, 0.f};
        acc[1] = (f32x4){0.f, 0.f, 0.f, 0.f};
        #pragma unroll
        for (int ks = 0; ks < 4; ++ks) {
            // B[c][o] frag = W[o][c], 8 contiguous c per lane, col o = lr
            bf16x8 wf = *(const bf16x8*)&W2[(nt * 16 + lr) * C_ + ks * 32 + grp * 8];
            acc[0] = __builtin_amdgcn_mfma_f32_16x16x32_bf16(afrag[0][ks], wf, acc[0], 0, 0, 0);
            acc[1] = __builtin_amdgcn_mfma_f32_16x16x32_bf16(afrag[1][ks], wf, acc[1], 0, 0, 0);
        }
        // D: col o = lr, rows t = grp*4+r.  Spill with bias.
        #pragma unroll
        for (int p = 0; p < 2; ++p) {
            int pos = wv * 2 + p;
            if (nt < 2) {                // q (nt=0) / k (nt=1): [pos][qk][t][o]
                #pragma unroll
                for (int r = 0; r < 4; ++r)
                    qk_lds[IDX_QK(pos, nt, grp * 4 + r, lr)] = f2bf(acc[p][r] + biasv[nt]);
            } else {                     // v transposed: [pos][c][t], b64 pack over t
                int c = (nt - 2) * 16 + lr;
                bf16x4 pk;
                #pragma unroll
                for (int r = 0; r < 4; ++r) pk[r] = (short)f2bf(acc[p][r] + biasv[nt]);
                *(bf16x4*)&vT_lds[IDX_V(pos, c, grp * 4)] = pk;
            }
        }
    }
    __syncthreads();   // B2: spills visible across lanes

    // ---- phase 3: scores^T -> softmax -> PV (mfma 16x16x16 bf16) ----------
    f32x4 oacc[2][8];
    #pragma unroll
    for (int p = 0; p < 2; ++p) {
        int pos = wv * 2 + p;
        // sT[j,i] = sum_o k[j,o] * q[i,o]: A = k (row j = lr), B = q (col i = lr)
        bf16x4 kf = *(const bf16x4*)&qk_lds[IDX_QK(pos, 1, lr, grp * 4)];
        bf16x4 qf = *(const bf16x4*)&qk_lds[IDX_QK(pos, 0, lr, grp * 4)];
        f32x4 s = (f32x4){0.f, 0.f, 0.f, 0.f};
        s = __builtin_amdgcn_mfma_f32_16x16x16bf16_1k(kf, qf, s, 0, 0, 0);
        // softmax over j (rows): lane holds 4 j's of col i=lr; reduce regs + groups
        float mx = fmaxf(fmaxf(s[0], s[1]), fmaxf(s[2], s[3]));
        mx = fmaxf(mx, __shfl_xor(mx, 16));
        mx = fmaxf(mx, __shfl_xor(mx, 32));
        float e0 = __expf(s[0] - mx), e1 = __expf(s[1] - mx);
        float e2 = __expf(s[2] - mx), e3 = __expf(s[3] - mx);
        float sm = e0 + e1 + e2 + e3;
        sm += __shfl_xor(sm, 16);
        sm += __shfl_xor(sm, 32);
        float inv = 1.0f / sm;
        // pT[j,i] is exactly the PV B-fragment layout (col i = lr, k j = grp*4+e)
        bf16x4 pf;
        pf[0] = (short)f2bf(e0 * inv); pf[1] = (short)f2bf(e1 * inv);
        pf[2] = (short)f2bf(e2 * inv); pf[3] = (short)f2bf(e3 * inv);
        // outT[c,i] = sum_j vT[c,j] pT[j,i]
        #pragma unroll
        for (int ct = 0; ct < 8; ++ct) {
            bf16x4 vf = *(const bf16x4*)&vT_lds[IDX_V(pos, ct * 16 + lr, grp * 4)];
            f32x4 z = (f32x4){0.f, 0.f, 0.f, 0.f};
            oacc[p][ct] = __builtin_amdgcn_mfma_f32_16x16x16bf16_1k(vf, pf, z, 0, 0, 0);
        }
    }
    __syncthreads();   // B3: everyone done reading x region (afrags) + vT

    // ---- phase 4: spill outT into [t][w][c] (reuses x region) -------------
    // D: col i = lr (=t), rows c = ct*16 + grp*4 + r (contiguous c -> b64 pack)
    #pragma unroll
    for (int p = 0; p < 2; ++p) {
        int pos = wv * 2 + p;
        #pragma unroll
        for (int ct = 0; ct < 8; ++ct) {
            bf16x4 pk;
            #pragma unroll
            for (int r = 0; r < 4; ++r) pk[r] = (short)f2bf(oacc[p][ct][r]);
            *(bf16x4*)&xo_lds[IDX_O(lr, pos, ct * 16 + grp * 4)] = pk;
        }
    }
    __syncthreads();   // B4

    // ---- phase 5: y = gamma*out + x, coalesced 64B rows --------------------
    {
        float g = gamma[0];
        #pragma unroll
        for (int k = 0; k < 4; ++k) {
            int rowid = tid + 512 * k;        // 0..2047 = t*128 + c
            int t = rowid >> 7, c = rowid & 127;
            const float* px = xb + c * (T_ * H_ * W_) + t * (H_ * W_);
            float*       py = yb + c * (T_ * H_ * W_) + t * (H_ * W_);
            #pragma unroll
            for (int q4 = 0; q4 < 4; ++q4) {
                f32x4 xv = *(const f32x4*)(px + q4 * 4);
                f32x4 rv;
                #pragma unroll
                for (int e = 0; e < 4; ++e) {
                    unsigned short s = xo_lds[IDX_O(t, q4 * 4 + e, c)];
                    rv[e] = fmaf(g, bf2f(s), xv[e]);
                }
                *(f32x4*)(py + q4 * 4) = rv;
            }
        }
    }
}

// ---------------- launch --------------------------------------------------------
extern "C" void kernel_launch(void* const* d_in, const int* in_sizes, int n_in,
                              void* d_out, int out_size, void* d_ws, size_t ws_size,
                              hipStream_t stream) {
    const float* x  = (const float*)d_in[0];
    const float* qw = (const float*)d_in[1];
    const float* qb = (const float*)d_in[2];
    const float* kw = (const float*)d_in[3];
    const float* kb = (const float*)d_in[4];
    const float* vw = (const float*)d_in[5];
    const float* vb = (const float*)d_in[6];
    const float* gm = (const float*)d_in[7];
    float* y = (float*)d_out;

    unsigned short* W2 = (unsigned short*)d_ws;                  // 160*128 bf16
    float* b2 = (float*)((char*)d_ws + CO_ * C_ * sizeof(unsigned short));

    tsa_prepack<<<80, 256, 0, stream>>>(qw, qb, kw, kb, vw, vb, W2, b2);
    tsa_main<<<NBLK, 512, 0, stream>>>(x, W2, b2, gm, y);
}

// Round 2
// 104.569 us; speedup vs baseline: 1.3551x; 1.3551x over previous
//
#include <hip/hip_runtime.h>

// TSA_24936580121000 — fused temporal self-attention, MI355X gfx950. Round 2.
// Changes vs R1: coalesced global access in stage/write phases (lane = 16B
// segment of a w-row, not a whole row), v kept in registers (D-layout of the
// v-projection == A-layout of PV, same lane), single time-shared 68KiB LDS
// buffer -> 2 blocks/CU.

#define C_  128
#define T_  16
#define H_  64
#define W_  64
#define CO_ 160          // 16 q + 16 k + 128 v
#define WT_ 16           // w positions per block
#define NBLK 1024        // 4 b * 64 h * 4 wtiles
#define THW (T_*H_*W_)

typedef float  f32x4  __attribute__((ext_vector_type(4)));
typedef short  bf16x4 __attribute__((ext_vector_type(4)));
typedef short  bf16x8 __attribute__((ext_vector_type(8)));

__device__ __forceinline__ unsigned short f2bf(float f) {
    union { float f; unsigned u; } v; v.f = f;
    unsigned r = v.u + 0x7fffu + ((v.u >> 16) & 1u);   // RNE
    return (unsigned short)(r >> 16);
}
__device__ __forceinline__ float bf2f(unsigned short s) {
    union { unsigned u; float f; } v; v.u = ((unsigned)s) << 16;
    return v.f;
}

// ---------------- prepack: fp32 weights -> bf16 W2[160][128], biases b2[160] ----
__global__ __launch_bounds__(256) void tsa_prepack(
        const float* __restrict__ qw, const float* __restrict__ qb,
        const float* __restrict__ kw, const float* __restrict__ kb,
        const float* __restrict__ vw, const float* __restrict__ vb,
        unsigned short* __restrict__ W2, float* __restrict__ b2) {
    int i = blockIdx.x * 256 + threadIdx.x;      // 80*256 == 20480 == 160*128
    int o = i >> 7, c = i & 127;
    float v = (o < 16) ? qw[o * C_ + c] : (o < 32) ? kw[(o - 16) * C_ + c]
                                                   : vw[(o - 32) * C_ + c];
    W2[i] = f2bf(v);
    if (i < CO_) b2[i] = (i < 16) ? qb[i] : (i < 32) ? kb[i - 16] : vb[i - 32];
}

// ---------------- LDS geometry (shorts) — ONE buffer, three time-shared views --
// x-stage:  [pos][t][c]   pos-stride PS=2184, t-stride TS=136  (34944 sh)
// qk:       [pos][2][t][o=16]                                  ( 8192 sh)
// out:      [t][w][c]     t-stride 2116, w-stride 132          (33856 sh)
#define PS 2184
#define TS 136
#define IDX_X(pos, t, c)      ((pos) * PS + (t) * TS + (c))
#define IDX_QK(pos, qk, t, o) (((((pos) * 2 + (qk)) * T_ + (t)) * 16) + (o))
#define OS_W 132
#define OS_T 2116
#define IDX_O(t, w, c)        ((t) * OS_T + (w) * OS_W + (c))
#define BUF_SH (T_ * PS)      // 34944 shorts = 69888 B  -> 2 blocks/CU

// ---------------- main fused kernel --------------------------------------------
__global__ __launch_bounds__(512, 4) void tsa_main(
        const float* __restrict__ x, const unsigned short* __restrict__ W2,
        const float* __restrict__ b2, const float* __restrict__ gamma,
        float* __restrict__ y) {

    __shared__ __align__(16) unsigned short buf[BUF_SH];

    // XCD-chunked swizzle (nwg=1024 % 8 == 0): 4 wtiles of one (b,h) row share an XCD.
    int bid  = blockIdx.x;
    int work = (bid & 7) * (NBLK / 8) + (bid >> 3);
    int bh = work >> 2;
    int wt = work & 3;
    int b  = bh >> 6, h = bh & 63;
    int w0 = wt * WT_;

    const size_t base = (size_t)b * C_ * THW + (size_t)h * W_ + w0;
    const float* xb = x + base;
    float*       yb = y + base;

    const int tid = threadIdx.x;
    const int wq  = tid & 3;          // 16B segment within the 64B w-row
    const int cs  = tid >> 2;         // channel 0..127
    const float g = gamma[0];         // hoisted off the critical tail

    // ---- phase 1: stage x tile -> bf16 LDS [pos][t][c], coalesced ----------
    // wave instr = 16 channels x full 64B row -> 16 fully-used lines.
    {
        const float* xcol = xb + (size_t)cs * THW + wq * 4;
        f32x4 pb = *(const f32x4*)(xcol);
        #pragma unroll
        for (int t = 0; t < T_; ++t) {
            f32x4 cur = pb;
            if (t + 1 < T_) pb = *(const f32x4*)(xcol + (t + 1) * (H_ * W_));
            #pragma unroll
            for (int e = 0; e < 4; ++e)
                buf[IDX_X(wq * 4 + e, t, cs)] = f2bf(cur[e]);
        }
    }

    const int wv  = tid >> 6;          // wave 0..7 -> positions wv*2, wv*2+1
    const int lr  = tid & 15;
    const int grp = (tid & 63) >> 4;

    float biasv[10];
    #pragma unroll
    for (int nt = 0; nt < 10; ++nt) biasv[nt] = b2[nt * 16 + lr];

    __syncthreads();   // B1: stage complete

    // ---- phase 2 pre: A-fragments (x[t][c]) to registers --------------------
    bf16x8 afrag[2][4];
    #pragma unroll
    for (int p = 0; p < 2; ++p)
        #pragma unroll
        for (int ks = 0; ks < 4; ++ks)
            afrag[p][ks] = *(const bf16x8*)&buf[IDX_X(wv * 2 + p, lr, ks * 32 + grp * 8)];

    __syncthreads();   // B1.5: qk region aliases x pos 0..3 — all reads done

    // ---- phase 2: qkv projection (mfma 16x16x32 bf16) -----------------------
    // v stays in registers: proj D-layout (col=o=lr, row=t=grp*4+r) IS the PV
    // A-layout (row=c=lr, k=j=grp*4+r) for the same lane.
    bf16x4 vreg[2][8];
    #pragma unroll
    for (int nt = 0; nt < 10; ++nt) {
        f32x4 acc0 = (f32x4){0.f, 0.f, 0.f, 0.f};
        f32x4 acc1 = (f32x4){0.f, 0.f, 0.f, 0.f};
        #pragma unroll
        for (int ks = 0; ks < 4; ++ks) {
            bf16x8 wf = *(const bf16x8*)&W2[(nt * 16 + lr) * C_ + ks * 32 + grp * 8];
            acc0 = __builtin_amdgcn_mfma_f32_16x16x32_bf16(afrag[0][ks], wf, acc0, 0, 0, 0);
            acc1 = __builtin_amdgcn_mfma_f32_16x16x32_bf16(afrag[1][ks], wf, acc1, 0, 0, 0);
        }
        if (nt < 2) {                 // q/k -> LDS (needs cross-lane transpose)
            #pragma unroll
            for (int r = 0; r < 4; ++r) {
                buf[IDX_QK(wv * 2 + 0, nt, grp * 4 + r, lr)] = f2bf(acc0[r] + biasv[nt]);
                buf[IDX_QK(wv * 2 + 1, nt, grp * 4 + r, lr)] = f2bf(acc1[r] + biasv[nt]);
            }
        } else {                      // v -> registers (bf16 packed)
            bf16x4 p0, p1;
            #pragma unroll
            for (int r = 0; r < 4; ++r) {
                p0[r] = (short)f2bf(acc0[r] + biasv[nt]);
                p1[r] = (short)f2bf(acc1[r] + biasv[nt]);
            }
            vreg[0][nt - 2] = p0;
            vreg[1][nt - 2] = p1;
        }
    }
    __syncthreads();   // B2: qk visible

    // ---- phase 3: scores^T -> softmax -> PV -> pack out bf16 ----------------
    bf16x4 obf[2][8];
    #pragma unroll
    for (int p = 0; p < 2; ++p) {
        int pos = wv * 2 + p;
        bf16x4 kf = *(const bf16x4*)&buf[IDX_QK(pos, 1, lr, grp * 4)];
        bf16x4 qf = *(const bf16x4*)&buf[IDX_QK(pos, 0, lr, grp * 4)];
        f32x4 s = (f32x4){0.f, 0.f, 0.f, 0.f};
        s = __builtin_amdgcn_mfma_f32_16x16x16bf16_1k(kf, qf, s, 0, 0, 0);
        // softmax over j (rows = grp*4+r): 4 regs + lane-groups via shfl
        float mx = fmaxf(fmaxf(s[0], s[1]), fmaxf(s[2], s[3]));
        mx = fmaxf(mx, __shfl_xor(mx, 16));
        mx = fmaxf(mx, __shfl_xor(mx, 32));
        float e0 = __expf(s[0] - mx), e1 = __expf(s[1] - mx);
        float e2 = __expf(s[2] - mx), e3 = __expf(s[3] - mx);
        float sm = e0 + e1 + e2 + e3;
        sm += __shfl_xor(sm, 16);
        sm += __shfl_xor(sm, 32);
        float inv = 1.0f / sm;
        bf16x4 pf;
        pf[0] = (short)f2bf(e0 * inv); pf[1] = (short)f2bf(e1 * inv);
        pf[2] = (short)f2bf(e2 * inv); pf[3] = (short)f2bf(e3 * inv);
        // outT[c][i] = sum_j vT[c][j] pT[j][i]; A = vreg (same-lane), B = pf
        #pragma unroll
        for (int ct = 0; ct < 8; ++ct) {
            f32x4 z = (f32x4){0.f, 0.f, 0.f, 0.f};
            z = __builtin_amdgcn_mfma_f32_16x16x16bf16_1k(vreg[p][ct], pf, z, 0, 0, 0);
            bf16x4 ob;
            #pragma unroll
            for (int r = 0; r < 4; ++r) ob[r] = (short)f2bf(z[r]);
            obf[p][ct] = ob;
        }
    }
    __syncthreads();   // B3: qk reads done — buffer becomes out region

    // ---- phase 4: spill outT -> LDS [t][w][c] -------------------------------
    #pragma unroll
    for (int p = 0; p < 2; ++p)
        #pragma unroll
        for (int ct = 0; ct < 8; ++ct)
            *(bf16x4*)&buf[IDX_O(lr, wv * 2 + p, ct * 16 + grp * 4)] = obf[p][ct];
    __syncthreads();   // B4

    // ---- phase 5: y = gamma*out + x, coalesced; x re-read is L3-hot ---------
    {
        const float* xrow = xb + (size_t)cs * THW + wq * 4;
        float*       yrow = yb + (size_t)cs * THW + wq * 4;
        f32x4 pb = *(const f32x4*)(xrow);
        #pragma unroll
        for (int t = 0; t < T_; ++t) {
            f32x4 xv = pb;
            if (t + 1 < T_) pb = *(const f32x4*)(xrow + (t + 1) * (H_ * W_));
            f32x4 rv;
            #pragma unroll
            for (int e = 0; e < 4; ++e)
                rv[e] = fmaf(g, bf2f(buf[IDX_O(t, wq * 4 + e, cs)]), xv[e]);
            *(f32x4*)(yrow + t * (H_ * W_)) = rv;
        }
    }
}

// ---------------- launch --------------------------------------------------------
extern "C" void kernel_launch(void* const* d_in, const int* in_sizes, int n_in,
                              void* d_out, int out_size, void* d_ws, size_t ws_size,
                              hipStream_t stream) {
    const float* x  = (const float*)d_in[0];
    const float* qw = (const float*)d_in[1];
    const float* qb = (const float*)d_in[2];
    const float* kw = (const float*)d_in[3];
    const float* kb = (const float*)d_in[4];
    const float* vw = (const float*)d_in[5];
    const float* vb = (const float*)d_in[6];
    const float* gm = (const float*)d_in[7];
    float* y = (float*)d_out;

    unsigned short* W2 = (unsigned short*)d_ws;                  // 160*128 bf16
    float* b2 = (float*)((char*)d_ws + CO_ * C_ * sizeof(unsigned short));

    tsa_prepack<<<80, 256, 0, stream>>>(qw, qb, kw, kb, vw, vb, W2, b2);
    tsa_main<<<NBLK, 512, 0, stream>>>(x, W2, b2, gm, y);
}